// Round 9
// baseline (188.100 us; speedup 1.0000x reference)
//
#include <hip/hip_runtime.h>

typedef unsigned short u16;
typedef __attribute__((ext_vector_type(4))) float f32x4;
typedef __attribute__((ext_vector_type(8))) short short8;

#define AS1 __attribute__((address_space(1)))
#define AS3 __attribute__((address_space(3)))

#define B_  2
#define T_  2048
#define C_  1024
#define H_  16
#define HD_ 64
#define N3C 3072
#define BT_ 4096

__device__ __forceinline__ u16 f2bf(float x) {
    unsigned u = __float_as_uint(x);
    u += 0x7fff + ((u >> 16) & 1);          // RTNE
    return (u16)(u >> 16);
}

// one-instruction packed fp32x2 -> bf16x2 (RTNE), gfx950
__device__ __forceinline__ unsigned cvt_pk_bf16(float a, float b) {
    unsigned r;
    asm("v_cvt_pk_bf16_f32 %0, %1, %2" : "=v"(r) : "v"(a), "v"(b));
    return r;
}

// ---------------------------------------------------------------------------
// Fused conversion kernel: blocks [0,4096) = x fp32->bf16;
// [4096,4864) = Wqkv transpose; [4864,5120) = Wproj transpose.
// ---------------------------------------------------------------------------
__global__ __launch_bounds__(256)
void conv_all(const float* __restrict__ x, u16* __restrict__ xb,
              const float* __restrict__ Wq, u16* __restrict__ WqT,
              const float* __restrict__ Wp, u16* __restrict__ WpT) {
    __shared__ float tile[64][68];
    const int tid = threadIdx.x;
    const int b = blockIdx.x;
    if (b < 4096) {
        int i = b * 256 + tid;
        float4 f = ((const float4*)x)[i];
        uint2 o;
        o.x = cvt_pk_bf16(f.x, f.y);
        o.y = cvt_pk_bf16(f.z, f.w);
        ((uint2*)xb)[i] = o;
        return;
    }
    const float* W; u16* WT; int N, k0, n0;
    if (b < 4096 + 768) {
        int bb = b - 4096; W = Wq; WT = WqT; N = N3C;
        n0 = (bb % 48) * 64; k0 = (bb / 48) * 64;
    } else {
        int bb = b - 4864; W = Wp; WT = WpT; N = C_;
        n0 = (bb % 16) * 64; k0 = (bb / 16) * 64;
    }
    #pragma unroll
    for (int i = 0; i < 4; ++i) {
        int slot = tid + i * 256;
        int row = slot >> 4, c4 = (slot & 15) * 4;
        *(float4*)&tile[row][c4] = *(const float4*)&W[(size_t)(k0 + row) * N + n0 + c4];
    }
    __syncthreads();
    #pragma unroll
    for (int i = 0; i < 4; ++i) {
        int slot = tid + i * 256;
        int nn = slot >> 4, k4 = (slot & 15) * 4;
        uint2 o;
        o.x = cvt_pk_bf16(tile[k4 + 0][nn], tile[k4 + 1][nn]);
        o.y = cvt_pk_bf16(tile[k4 + 2][nn], tile[k4 + 3][nn]);
        *(uint2*)&WT[(size_t)(n0 + nn) * 1024 + k0 + k4] = o;
    }
}

// ---------------------------------------------------------------------------
// bf16 MFMA GEMM core (128x128, BK=64), double-buffered LDS, raw s_barrier,
// fine vmcnt(8) so next tile's global_load_lds stay in flight.
// ---------------------------------------------------------------------------
__device__ __forceinline__ void gemm_core(const u16* __restrict__ A, const u16* __restrict__ BT,
                                          u16* As, u16* Bs,    // [2][128*64] each
                                          int m0, int n0, f32x4 (&acc)[4][4]) {
    const int tid = threadIdx.x;
    const int lane = tid & 63, w = tid >> 6;
    const int l15 = lane & 15, quad = lane >> 4;
    const int row0 = (w >> 1) * 64, col0 = (w & 1) * 64;
    const int srow = lane >> 3;
    const int schunk = (lane & 7) ^ srow;

    auto stage = [&](int buf, int k0) {
        #pragma unroll
        for (int j = 0; j < 4; ++j) {
            int rbase = w * 32 + j * 8;
            const u16* ga = A  + (size_t)(m0 + rbase + srow) * 1024 + k0 + schunk * 8;
            const u16* gb = BT + (size_t)(n0 + rbase + srow) * 1024 + k0 + schunk * 8;
            __builtin_amdgcn_global_load_lds((const AS1 void*)ga,
                (AS3 void*)(As + buf * (128 * 64) + rbase * 64), 16, 0, 0);
            __builtin_amdgcn_global_load_lds((const AS1 void*)gb,
                (AS3 void*)(Bs + buf * (128 * 64) + rbase * 64), 16, 0, 0);
        }
    };

    stage(0, 0);
    #pragma unroll
    for (int it = 0; it < 16; ++it) {
        const int cur = it & 1;
        if (it + 1 < 16) {
            stage(cur ^ 1, (it + 1) * 64);
            asm volatile("s_waitcnt vmcnt(8)\n\ts_barrier" ::: "memory");
        } else {
            asm volatile("s_waitcnt vmcnt(0)\n\ts_barrier" ::: "memory");
        }
        const u16* Ac = As + cur * (128 * 64);
        const u16* Bc = Bs + cur * (128 * 64);
        #pragma unroll
        for (int s = 0; s < 2; ++s) {
            short8 a[4], b[4];
            #pragma unroll
            for (int rt = 0; rt < 4; ++rt) {
                int row = row0 + rt * 16 + l15;
                a[rt] = *(const short8*)&Ac[row * 64 + (((s * 4 + quad) ^ (l15 & 7)) * 8)];
            }
            #pragma unroll
            for (int ct = 0; ct < 4; ++ct) {
                int row = col0 + ct * 16 + l15;
                b[ct] = *(const short8*)&Bc[row * 64 + (((s * 4 + quad) ^ (l15 & 7)) * 8)];
            }
            #pragma unroll
            for (int rt = 0; rt < 4; ++rt)
                #pragma unroll
                for (int ct = 0; ct < 4; ++ct)
                    acc[rt][ct] = __builtin_amdgcn_mfma_f32_16x16x32_bf16(a[rt], b[ct], acc[rt][ct], 0, 0, 0);
        }
        asm volatile("s_waitcnt lgkmcnt(0)\n\ts_barrier" ::: "memory");
    }
}

// ---------------------------------------------------------------------------
// QKV GEMM: q,k -> [B,H,T,HD];  v -> [B,H,HD,T].
// q pre-scaled by 1/8 * log2(e) so attention can use exp2 (v_exp_f32 direct).
// ---------------------------------------------------------------------------
__global__ __launch_bounds__(256)
void qkv_gemm(const u16* __restrict__ A, const u16* __restrict__ BT,
              const float* __restrict__ bias,
              u16* __restrict__ q, u16* __restrict__ k, u16* __restrict__ vT) {
    __shared__ __align__(16) u16 As[2 * 128 * 64];
    __shared__ __align__(16) u16 Bs[2 * 128 * 64];
    const int m0 = blockIdx.y * 128, n0 = blockIdx.x * 128;
    f32x4 acc[4][4] = {};
    gemm_core(A, BT, As, Bs, m0, n0, acc);

    const int tid = threadIdx.x;
    const int lane = tid & 63, w = tid >> 6;
    const int l15 = lane & 15, quad = lane >> 4;
    const int row0 = (w >> 1) * 64, col0 = (w & 1) * 64;
    const int which = n0 >> 10;
    const float QSCALE = 0.125f * 1.4426950408889634f;   // 1/8 * log2(e)

    #pragma unroll
    for (int ct = 0; ct < 4; ++ct) {
        int n = n0 + col0 + ct * 16 + l15;
        int nl = n & 1023, h = nl >> 6, d = nl & 63;
        float bv = bias[n];
        #pragma unroll
        for (int rt = 0; rt < 4; ++rt) {
            int mb = m0 + row0 + rt * 16 + quad * 4;
            int bb = mb >> 11, t0 = mb & 2047;
            f32x4 v4 = acc[rt][ct];
            if (which == 0) {
                size_t base = ((size_t)(bb * H_ + h) * T_ + t0) * HD_ + d;
                #pragma unroll
                for (int r = 0; r < 4; ++r)
                    q[base + (size_t)r * HD_] = f2bf((v4[r] + bv) * QSCALE);
            } else if (which == 1) {
                size_t base = ((size_t)(bb * H_ + h) * T_ + t0) * HD_ + d;
                #pragma unroll
                for (int r = 0; r < 4; ++r)
                    k[base + (size_t)r * HD_] = f2bf(v4[r] + bv);
            } else {
                uint2 o;
                o.x = cvt_pk_bf16(v4[0] + bv, v4[1] + bv);
                o.y = cvt_pk_bf16(v4[2] + bv, v4[3] + bv);
                *(uint2*)&vT[((size_t)(bb * H_ + h) * HD_ + d) * T_ + t0] = o;
            }
        }
    }
}

// ---------------------------------------------------------------------------
// Flash attention v6: uniform-work blocks (strip pair {s, 63-s}, 32 q-rows
// each, 2 waves per strip), LDS = K/V dbuf only (32 KB -> 4+ blocks/CU).
// P is written into the DEAD half of Ks[cur] (K frags already in regs,
// enforced by the mid lgkm+barrier); each wave's P slice = the same 16 rows
// it stages, so no end-of-phase barrier is needed.  2 barriers/phase.
// S^T = K.Q^T, unnormalized exp2 (log2e folded into q upstream).
// ---------------------------------------------------------------------------
__global__ __launch_bounds__(256, 4)
void attn(const u16* __restrict__ q, const u16* __restrict__ k,
          const u16* __restrict__ vT, u16* __restrict__ y) {
    __shared__ __align__(16) u16 Ks[2 * 64 * 64];
    __shared__ __align__(16) u16 Vs[2 * 64 * 64];
    const int tid = threadIdx.x;
    const int lane = tid & 63, w = tid >> 6;
    const int l15 = lane & 15, quad = lane >> 4;
    const int srow = lane >> 3, schunk = (lane & 7) ^ srow;
    const int idx = blockIdx.x;
    const int bh = idx & 31;                        // bh%8 = XCD locality
    const int pr = idx >> 5;                        // 0..31
    const int strip = (w >= 2) ? (63 - pr) : pr;    // 32-row q-strip per wave pair
    const int myktmax = strip >> 1;
    const int ktmax = (63 - pr) >> 1;               // heavy strip bound
    const u16* qp = q  + (size_t)bh * T_ * HD_;
    const u16* kp = k  + (size_t)bh * T_ * HD_;
    const u16* vp = vT + (size_t)bh * HD_ * T_;

    const int qrow = strip * 32 + (w & 1) * 16 + l15;
    short8 qf[2];
    #pragma unroll
    for (int s = 0; s < 2; ++s)
        qf[s] = *(const short8*)&qp[(size_t)qrow * HD_ + s * 32 + quad * 8];

    auto stage = [&](int buf, int kt) {
        const int kb = kt * 64;
        #pragma unroll
        for (int j = 0; j < 2; ++j) {
            int row = w * 16 + j * 8 + srow;
            __builtin_amdgcn_global_load_lds(
                (const AS1 void*)(kp + (size_t)(kb + row) * HD_ + schunk * 8),
                (AS3 void*)(Ks + buf * (64 * 64) + (w * 16 + j * 8) * 64), 16, 0, 0);
            __builtin_amdgcn_global_load_lds(
                (const AS1 void*)(vp + (size_t)row * T_ + kb + schunk * 8),
                (AS3 void*)(Vs + buf * (64 * 64) + (w * 16 + j * 8) * 64), 16, 0, 0);
        }
    };

    f32x4 o[4] = {};
    float l = 0.f;
    stage(0, 0);

    for (int kt = 0; kt <= ktmax; ++kt) {
        const int kb = kt * 64;
        const int cur = kt & 1;
        if (kt < ktmax) {
            stage(cur ^ 1, kt + 1);
            asm volatile("s_waitcnt vmcnt(4)\n\ts_barrier" ::: "memory");
        } else {
            asm volatile("s_waitcnt vmcnt(0)\n\ts_barrier" ::: "memory");
        }
        u16* Kc = Ks + cur * (64 * 64);
        const u16* Vc = Vs + cur * (64 * 64);
        const bool active = (kt <= myktmax);        // wave-uniform

        short8 ka[4][2], va[4][2];
        if (active) {
            #pragma unroll
            for (int ct = 0; ct < 4; ++ct)
                #pragma unroll
                for (int s = 0; s < 2; ++s) {
                    int xo = ((s * 4 + quad) ^ (l15 & 7)) * 8;
                    ka[ct][s] = *(const short8*)&Kc[(ct * 16 + l15) * 64 + xo];
                    va[ct][s] = *(const short8*)&Vc[(ct * 16 + l15) * 64 + xo];
                }
        }
        // all waves' K/V fragment reads complete before P overwrites Ks[cur]
        asm volatile("s_waitcnt lgkmcnt(0)\n\ts_barrier" ::: "memory");

        if (active) {
            // S^T = K.Q^T  (C row = key, col = q = l15);  scores already *log2e
            f32x4 st[4] = {};
            #pragma unroll
            for (int s = 0; s < 2; ++s)
                #pragma unroll
                for (int ct = 0; ct < 4; ++ct)
                    st[ct] = __builtin_amdgcn_mfma_f32_16x16x32_bf16(ka[ct][s], qf[s], st[ct], 0, 0, 0);

            float pe[16];
            #pragma unroll
            for (int ct = 0; ct < 4; ++ct)
                #pragma unroll
                for (int r = 0; r < 4; ++r)
                    pe[ct * 4 + r] = exp2f(st[ct][r]);
            if (kt == myktmax) {                    // wave-uniform causal mask
                #pragma unroll
                for (int ct = 0; ct < 4; ++ct)
                    #pragma unroll
                    for (int r = 0; r < 4; ++r)
                        if ((kb + ct * 16 + quad * 4 + r) > qrow) pe[ct * 4 + r] = 0.f;
            }
            float psum = 0.f;
            #pragma unroll
            for (int i = 0; i < 16; ++i) psum += pe[i];
            l += psum;

            // P -> dead Ks[cur], wave-own rows w*16.., stride 64, XOR chunks
            u16* Pw = Kc + (w * 16 + l15) * 64;
            #pragma unroll
            for (int ct = 0; ct < 4; ++ct) {
                int chunk = ct * 2 + (quad >> 1);
                int off = ((chunk ^ (l15 & 7)) << 3) + (quad & 1) * 4;
                uint2 pk;
                pk.x = cvt_pk_bf16(pe[ct * 4 + 0], pe[ct * 4 + 1]);
                pk.y = cvt_pk_bf16(pe[ct * 4 + 2], pe[ct * 4 + 3]);
                *(uint2*)&Pw[off] = pk;
            }
            asm volatile("s_waitcnt lgkmcnt(0)" ::: "memory");   // wave-local RT

            // O^T = V^T . P^T
            #pragma unroll
            for (int s = 0; s < 2; ++s) {
                short8 pb = *(const short8*)&Pw[(((s * 4 + quad) ^ (l15 & 7)) << 3)];
                #pragma unroll
                for (int n = 0; n < 4; ++n)
                    o[n] = __builtin_amdgcn_mfma_f32_16x16x32_bf16(va[n][s], pb, o[n], 0, 0, 0);
            }
        }
        // no end barrier: each wave's P slice / stage rows are disjoint per wave
    }

    l += __shfl_xor(l, 16); l += __shfl_xor(l, 32);
    const float inv = 1.f / l;
    const int bb = bh >> 4, h = bh & 15;
    #pragma unroll
    for (int n = 0; n < 4; ++n) {
        uint2 pk;
        pk.x = cvt_pk_bf16(o[n][0] * inv, o[n][1] * inv);
        pk.y = cvt_pk_bf16(o[n][2] * inv, o[n][3] * inv);
        *(uint2*)&y[((size_t)(bb * T_ + qrow)) * C_ + h * 64 + n * 16 + quad * 4] = pk;
    }
}

// ---------------------------------------------------------------------------
// Output projection: y[4096][1024] @ WprojT[1024][1024]^T + bias -> fp32 out.
// 128x64 tile (512 blocks, 48 KB LDS -> 3 blocks/CU vs 1 at 128x128).
// ---------------------------------------------------------------------------
__global__ __launch_bounds__(256, 3)
void proj_gemm(const u16* __restrict__ A, const u16* __restrict__ BT,
               const float* __restrict__ bias, float* __restrict__ out) {
    __shared__ __align__(16) u16 As[2 * 128 * 64];
    __shared__ __align__(16) u16 Bs[2 * 64 * 64];
    const int m0 = blockIdx.y * 128, n0 = blockIdx.x * 64;
    const int tid = threadIdx.x;
    const int lane = tid & 63, w = tid >> 6;
    const int l15 = lane & 15, quad = lane >> 4;
    const int row0 = (w & 1) * 64, col0 = (w >> 1) * 32;
    const int srow = lane >> 3;
    const int schunk = (lane & 7) ^ srow;
    f32x4 acc[4][2] = {};

    auto stage = [&](int buf, int k0) {
        #pragma unroll
        for (int j = 0; j < 4; ++j) {
            int rbase = w * 32 + j * 8;
            const u16* ga = A + (size_t)(m0 + rbase + srow) * 1024 + k0 + schunk * 8;
            __builtin_amdgcn_global_load_lds((const AS1 void*)ga,
                (AS3 void*)(As + buf * (128 * 64) + rbase * 64), 16, 0, 0);
        }
        #pragma unroll
        for (int j = 0; j < 2; ++j) {
            int rbase = w * 16 + j * 8;
            const u16* gb = BT + (size_t)(n0 + rbase + srow) * 1024 + k0 + schunk * 8;
            __builtin_amdgcn_global_load_lds((const AS1 void*)gb,
                (AS3 void*)(Bs + buf * (64 * 64) + rbase * 64), 16, 0, 0);
        }
    };

    stage(0, 0);
    #pragma unroll
    for (int it = 0; it < 16; ++it) {
        const int cur = it & 1;
        if (it + 1 < 16) {
            stage(cur ^ 1, (it + 1) * 64);
            asm volatile("s_waitcnt vmcnt(6)\n\ts_barrier" ::: "memory");
        } else {
            asm volatile("s_waitcnt vmcnt(0)\n\ts_barrier" ::: "memory");
        }
        const u16* Ac = As + cur * (128 * 64);
        const u16* Bc = Bs + cur * (64 * 64);
        #pragma unroll
        for (int s = 0; s < 2; ++s) {
            short8 a[4], b[2];
            #pragma unroll
            for (int rt = 0; rt < 4; ++rt) {
                int row = row0 + rt * 16 + l15;
                a[rt] = *(const short8*)&Ac[row * 64 + (((s * 4 + quad) ^ (l15 & 7)) * 8)];
            }
            #pragma unroll
            for (int ct = 0; ct < 2; ++ct) {
                int row = col0 + ct * 16 + l15;
                b[ct] = *(const short8*)&Bc[row * 64 + (((s * 4 + quad) ^ (l15 & 7)) * 8)];
            }
            #pragma unroll
            for (int rt = 0; rt < 4; ++rt)
                #pragma unroll
                for (int ct = 0; ct < 2; ++ct)
                    acc[rt][ct] = __builtin_amdgcn_mfma_f32_16x16x32_bf16(a[rt], b[ct], acc[rt][ct], 0, 0, 0);
        }
        asm volatile("s_waitcnt lgkmcnt(0)\n\ts_barrier" ::: "memory");
    }

    #pragma unroll
    for (int ct = 0; ct < 2; ++ct) {
        int n = n0 + col0 + ct * 16 + l15;
        float bv = bias[n];
        #pragma unroll
        for (int rt = 0; rt < 4; ++rt) {
            int mb = m0 + row0 + rt * 16 + quad * 4;
            f32x4 v4 = acc[rt][ct];
            #pragma unroll
            for (int r = 0; r < 4; ++r)
                out[(size_t)(mb + r) * 1024 + n] = v4[r] + bv;
        }
    }
}

// ---------------------------------------------------------------------------
extern "C" void kernel_launch(void* const* d_in, const int* in_sizes, int n_in,
                              void* d_out, int out_size, void* d_ws, size_t ws_size,
                              hipStream_t stream) {
    const float* x     = (const float*)d_in[0];
    const float* Wqkv  = (const float*)d_in[1];
    const float* bqkv  = (const float*)d_in[2];
    const float* Wproj = (const float*)d_in[3];
    const float* bproj = (const float*)d_in[4];

    u16* xb     = (u16*)d_ws;
    u16* WqkvT  = xb + (size_t)4 * 1024 * 1024;
    u16* WprojT = WqkvT + (size_t)3 * 1024 * 1024;
    u16* q      = WprojT + (size_t)1024 * 1024;
    u16* kk     = q + (size_t)4 * 1024 * 1024;
    u16* vT     = kk + (size_t)4 * 1024 * 1024;
    u16* y      = vT + (size_t)4 * 1024 * 1024;

    conv_all<<<5120, 256, 0, stream>>>(x, xb, Wqkv, WqkvT, Wproj, WprojT);
    qkv_gemm<<<dim3(N3C / 128, BT_ / 128), 256, 0, stream>>>(xb, WqkvT, bqkv, q, kk, vT);
    attn<<<1024, 256, 0, stream>>>(q, kk, vT, y);
    proj_gemm<<<dim3(C_ / 64, BT_ / 128), 256, 0, stream>>>(y, WprojT, bproj, (float*)d_out);
}

// Round 10
// 180.226 us; speedup vs baseline: 1.0437x; 1.0437x over previous
//
#include <hip/hip_runtime.h>

typedef unsigned short u16;
typedef __attribute__((ext_vector_type(4))) float f32x4;
typedef __attribute__((ext_vector_type(8))) short short8;

#define AS1 __attribute__((address_space(1)))
#define AS3 __attribute__((address_space(3)))

#define B_  2
#define T_  2048
#define C_  1024
#define H_  16
#define HD_ 64
#define N3C 3072
#define BT_ 4096

__device__ __forceinline__ u16 f2bf(float x) {
    unsigned u = __float_as_uint(x);
    u += 0x7fff + ((u >> 16) & 1);          // RTNE
    return (u16)(u >> 16);
}

// one-instruction packed fp32x2 -> bf16x2 (RTNE), gfx950
__device__ __forceinline__ unsigned cvt_pk_bf16(float a, float b) {
    unsigned r;
    asm("v_cvt_pk_bf16_f32 %0, %1, %2" : "=v"(r) : "v"(a), "v"(b));
    return r;
}

// ---------------------------------------------------------------------------
// Fused conversion kernel: blocks [0,4096) = x fp32->bf16;
// [4096,4864) = Wqkv transpose; [4864,5120) = Wproj transpose.
// ---------------------------------------------------------------------------
__global__ __launch_bounds__(256)
void conv_all(const float* __restrict__ x, u16* __restrict__ xb,
              const float* __restrict__ Wq, u16* __restrict__ WqT,
              const float* __restrict__ Wp, u16* __restrict__ WpT) {
    __shared__ float tile[64][68];
    const int tid = threadIdx.x;
    const int b = blockIdx.x;
    if (b < 4096) {
        int i = b * 256 + tid;
        float4 f = ((const float4*)x)[i];
        uint2 o;
        o.x = cvt_pk_bf16(f.x, f.y);
        o.y = cvt_pk_bf16(f.z, f.w);
        ((uint2*)xb)[i] = o;
        return;
    }
    const float* W; u16* WT; int N, k0, n0;
    if (b < 4096 + 768) {
        int bb = b - 4096; W = Wq; WT = WqT; N = N3C;
        n0 = (bb % 48) * 64; k0 = (bb / 48) * 64;
    } else {
        int bb = b - 4864; W = Wp; WT = WpT; N = C_;
        n0 = (bb % 16) * 64; k0 = (bb / 16) * 64;
    }
    #pragma unroll
    for (int i = 0; i < 4; ++i) {
        int slot = tid + i * 256;
        int row = slot >> 4, c4 = (slot & 15) * 4;
        *(float4*)&tile[row][c4] = *(const float4*)&W[(size_t)(k0 + row) * N + n0 + c4];
    }
    __syncthreads();
    #pragma unroll
    for (int i = 0; i < 4; ++i) {
        int slot = tid + i * 256;
        int nn = slot >> 4, k4 = (slot & 15) * 4;
        uint2 o;
        o.x = cvt_pk_bf16(tile[k4 + 0][nn], tile[k4 + 1][nn]);
        o.y = cvt_pk_bf16(tile[k4 + 2][nn], tile[k4 + 3][nn]);
        *(uint2*)&WT[(size_t)(n0 + nn) * 1024 + k0 + k4] = o;
    }
}

// ---------------------------------------------------------------------------
// bf16 MFMA GEMM core (128x128, BK=64), double-buffered LDS, raw s_barrier,
// fine vmcnt(8) so next tile's global_load_lds stay in flight.
// ---------------------------------------------------------------------------
__device__ __forceinline__ void gemm_core(const u16* __restrict__ A, const u16* __restrict__ BT,
                                          u16* As, u16* Bs,    // [2][128*64] each
                                          int m0, int n0, f32x4 (&acc)[4][4]) {
    const int tid = threadIdx.x;
    const int lane = tid & 63, w = tid >> 6;
    const int l15 = lane & 15, quad = lane >> 4;
    const int row0 = (w >> 1) * 64, col0 = (w & 1) * 64;
    const int srow = lane >> 3;
    const int schunk = (lane & 7) ^ srow;

    auto stage = [&](int buf, int k0) {
        #pragma unroll
        for (int j = 0; j < 4; ++j) {
            int rbase = w * 32 + j * 8;
            const u16* ga = A  + (size_t)(m0 + rbase + srow) * 1024 + k0 + schunk * 8;
            const u16* gb = BT + (size_t)(n0 + rbase + srow) * 1024 + k0 + schunk * 8;
            __builtin_amdgcn_global_load_lds((const AS1 void*)ga,
                (AS3 void*)(As + buf * (128 * 64) + rbase * 64), 16, 0, 0);
            __builtin_amdgcn_global_load_lds((const AS1 void*)gb,
                (AS3 void*)(Bs + buf * (128 * 64) + rbase * 64), 16, 0, 0);
        }
    };

    stage(0, 0);
    #pragma unroll
    for (int it = 0; it < 16; ++it) {
        const int cur = it & 1;
        if (it + 1 < 16) {
            stage(cur ^ 1, (it + 1) * 64);
            asm volatile("s_waitcnt vmcnt(8)\n\ts_barrier" ::: "memory");
        } else {
            asm volatile("s_waitcnt vmcnt(0)\n\ts_barrier" ::: "memory");
        }
        const u16* Ac = As + cur * (128 * 64);
        const u16* Bc = Bs + cur * (128 * 64);
        #pragma unroll
        for (int s = 0; s < 2; ++s) {
            short8 a[4], b[4];
            #pragma unroll
            for (int rt = 0; rt < 4; ++rt) {
                int row = row0 + rt * 16 + l15;
                a[rt] = *(const short8*)&Ac[row * 64 + (((s * 4 + quad) ^ (l15 & 7)) * 8)];
            }
            #pragma unroll
            for (int ct = 0; ct < 4; ++ct) {
                int row = col0 + ct * 16 + l15;
                b[ct] = *(const short8*)&Bc[row * 64 + (((s * 4 + quad) ^ (l15 & 7)) * 8)];
            }
            #pragma unroll
            for (int rt = 0; rt < 4; ++rt)
                #pragma unroll
                for (int ct = 0; ct < 4; ++ct)
                    acc[rt][ct] = __builtin_amdgcn_mfma_f32_16x16x32_bf16(a[rt], b[ct], acc[rt][ct], 0, 0, 0);
        }
        asm volatile("s_waitcnt lgkmcnt(0)\n\ts_barrier" ::: "memory");
    }
}

// ---------------------------------------------------------------------------
// QKV GEMM: q,k -> [B,H,T,HD];  v -> [B,H,HD,T].
// q pre-scaled by 1/8 * log2(e) so attention can use exp2 (v_exp_f32 direct).
// ---------------------------------------------------------------------------
__global__ __launch_bounds__(256)
void qkv_gemm(const u16* __restrict__ A, const u16* __restrict__ BT,
              const float* __restrict__ bias,
              u16* __restrict__ q, u16* __restrict__ k, u16* __restrict__ vT) {
    __shared__ __align__(16) u16 As[2 * 128 * 64];
    __shared__ __align__(16) u16 Bs[2 * 128 * 64];
    const int m0 = blockIdx.y * 128, n0 = blockIdx.x * 128;
    f32x4 acc[4][4] = {};
    gemm_core(A, BT, As, Bs, m0, n0, acc);

    const int tid = threadIdx.x;
    const int lane = tid & 63, w = tid >> 6;
    const int l15 = lane & 15, quad = lane >> 4;
    const int row0 = (w >> 1) * 64, col0 = (w & 1) * 64;
    const int which = n0 >> 10;
    const float QSCALE = 0.125f * 1.4426950408889634f;   // 1/8 * log2(e)

    #pragma unroll
    for (int ct = 0; ct < 4; ++ct) {
        int n = n0 + col0 + ct * 16 + l15;
        int nl = n & 1023, h = nl >> 6, d = nl & 63;
        float bv = bias[n];
        #pragma unroll
        for (int rt = 0; rt < 4; ++rt) {
            int mb = m0 + row0 + rt * 16 + quad * 4;
            int bb = mb >> 11, t0 = mb & 2047;
            f32x4 v4 = acc[rt][ct];
            if (which == 0) {
                size_t base = ((size_t)(bb * H_ + h) * T_ + t0) * HD_ + d;
                #pragma unroll
                for (int r = 0; r < 4; ++r)
                    q[base + (size_t)r * HD_] = f2bf((v4[r] + bv) * QSCALE);
            } else if (which == 1) {
                size_t base = ((size_t)(bb * H_ + h) * T_ + t0) * HD_ + d;
                #pragma unroll
                for (int r = 0; r < 4; ++r)
                    k[base + (size_t)r * HD_] = f2bf(v4[r] + bv);
            } else {
                uint2 o;
                o.x = cvt_pk_bf16(v4[0] + bv, v4[1] + bv);
                o.y = cvt_pk_bf16(v4[2] + bv, v4[3] + bv);
                *(uint2*)&vT[((size_t)(bb * H_ + h) * HD_ + d) * T_ + t0] = o;
            }
        }
    }
}

// ---------------------------------------------------------------------------
// Flash attention v7 = R8 work distribution + R9 LDS diet:
// one 64-row q-tile per block (1024 blocks, heavy first -> dynamic backfill,
// ALL 4 waves active every phase; 16.9k total block-phases).  LDS = K/V dbuf
// only (32 KB); P written into the DEAD half of Ks[cur] (K/V frags already in
// regs, enforced by mid lgkm+barrier).  2 barriers/phase.  S^T = K.Q^T,
// unnormalized exp2 (log2e folded into q upstream).
// ---------------------------------------------------------------------------
__global__ __launch_bounds__(256, 4)
void attn(const u16* __restrict__ q, const u16* __restrict__ k,
          const u16* __restrict__ vT, u16* __restrict__ y) {
    __shared__ __align__(16) u16 Ks[2 * 64 * 64];
    __shared__ __align__(16) u16 Vs[2 * 64 * 64];
    const int tid = threadIdx.x;
    const int lane = tid & 63, w = tid >> 6;
    const int l15 = lane & 15, quad = lane >> 4;
    const int srow = lane >> 3, schunk = (lane & 7) ^ srow;
    const int idx = blockIdx.x;
    const int bh = idx & 31;                        // bh%8 = XCD locality
    const int qt = 31 - (idx >> 5);                 // heavy first
    const u16* qp = q  + (size_t)bh * T_ * HD_;
    const u16* kp = k  + (size_t)bh * T_ * HD_;
    const u16* vp = vT + (size_t)bh * HD_ * T_;

    const int qrow = qt * 64 + w * 16 + l15;
    short8 qf[2];
    #pragma unroll
    for (int s = 0; s < 2; ++s)
        qf[s] = *(const short8*)&qp[(size_t)qrow * HD_ + s * 32 + quad * 8];

    auto stage = [&](int buf, int kt) {
        const int kb = kt * 64;
        // wave-local fence: previous phase's P reads (same rows, other buffer
        // half) must retire before the DMA write can be issued/hoisted here.
        asm volatile("s_waitcnt lgkmcnt(0)" ::: "memory");
        #pragma unroll
        for (int j = 0; j < 2; ++j) {
            int row = w * 16 + j * 8 + srow;
            __builtin_amdgcn_global_load_lds(
                (const AS1 void*)(kp + (size_t)(kb + row) * HD_ + schunk * 8),
                (AS3 void*)(Ks + buf * (64 * 64) + (w * 16 + j * 8) * 64), 16, 0, 0);
            __builtin_amdgcn_global_load_lds(
                (const AS1 void*)(vp + (size_t)row * T_ + kb + schunk * 8),
                (AS3 void*)(Vs + buf * (64 * 64) + (w * 16 + j * 8) * 64), 16, 0, 0);
        }
    };

    f32x4 o[4] = {};
    float l = 0.f;
    stage(0, 0);

    for (int kt = 0; kt <= qt; ++kt) {
        const int kb = kt * 64;
        const int cur = kt & 1;
        if (kt < qt) {
            stage(cur ^ 1, kt + 1);
            asm volatile("s_waitcnt vmcnt(4)\n\ts_barrier" ::: "memory");
        } else {
            asm volatile("s_waitcnt vmcnt(0)\n\ts_barrier" ::: "memory");
        }
        u16* Kc = Ks + cur * (64 * 64);
        const u16* Vc = Vs + cur * (64 * 64);

        short8 ka[4][2], va[4][2];
        #pragma unroll
        for (int ct = 0; ct < 4; ++ct)
            #pragma unroll
            for (int s = 0; s < 2; ++s) {
                int xo = ((s * 4 + quad) ^ (l15 & 7)) * 8;
                ka[ct][s] = *(const short8*)&Kc[(ct * 16 + l15) * 64 + xo];
                va[ct][s] = *(const short8*)&Vc[(ct * 16 + l15) * 64 + xo];
            }
        // all waves' K/V fragment reads complete before P overwrites Ks[cur]
        asm volatile("s_waitcnt lgkmcnt(0)\n\ts_barrier" ::: "memory");

        // S^T = K.Q^T  (C row = key, col = q = l15);  scores already *log2e
        f32x4 st[4] = {};
        #pragma unroll
        for (int s = 0; s < 2; ++s)
            #pragma unroll
            for (int ct = 0; ct < 4; ++ct)
                st[ct] = __builtin_amdgcn_mfma_f32_16x16x32_bf16(ka[ct][s], qf[s], st[ct], 0, 0, 0);

        float pe[16];
        #pragma unroll
        for (int ct = 0; ct < 4; ++ct)
            #pragma unroll
            for (int r = 0; r < 4; ++r)
                pe[ct * 4 + r] = exp2f(st[ct][r]);
        if (kt == qt) {                              // wave-uniform causal mask
            #pragma unroll
            for (int ct = 0; ct < 4; ++ct)
                #pragma unroll
                for (int r = 0; r < 4; ++r)
                    if ((kb + ct * 16 + quad * 4 + r) > qrow) pe[ct * 4 + r] = 0.f;
        }
        float psum = 0.f;
        #pragma unroll
        for (int i = 0; i < 16; ++i) psum += pe[i];
        l += psum;

        // P -> dead Ks[cur], wave-own rows w*16.., stride 64, XOR chunks
        u16* Pw = Kc + (w * 16 + l15) * 64;
        #pragma unroll
        for (int ct = 0; ct < 4; ++ct) {
            int chunk = ct * 2 + (quad >> 1);
            int off = ((chunk ^ (l15 & 7)) << 3) + (quad & 1) * 4;
            uint2 pk;
            pk.x = cvt_pk_bf16(pe[ct * 4 + 0], pe[ct * 4 + 1]);
            pk.y = cvt_pk_bf16(pe[ct * 4 + 2], pe[ct * 4 + 3]);
            *(uint2*)&Pw[off] = pk;
        }
        asm volatile("s_waitcnt lgkmcnt(0)" ::: "memory");   // wave-local RT

        // O^T = V^T . P^T
        #pragma unroll
        for (int s = 0; s < 2; ++s) {
            short8 pb = *(const short8*)&Pw[(((s * 4 + quad) ^ (l15 & 7)) << 3)];
            #pragma unroll
            for (int n = 0; n < 4; ++n)
                o[n] = __builtin_amdgcn_mfma_f32_16x16x32_bf16(va[n][s], pb, o[n], 0, 0, 0);
        }
        // no end barrier: P rows are wave-private; cross-wave safety is the
        // mid lgkm+barrier, buffer reuse safety is the top vmcnt+barrier.
    }

    l += __shfl_xor(l, 16); l += __shfl_xor(l, 32);
    const float inv = 1.f / l;
    const int bb = bh >> 4, h = bh & 15;
    #pragma unroll
    for (int n = 0; n < 4; ++n) {
        uint2 pk;
        pk.x = cvt_pk_bf16(o[n][0] * inv, o[n][1] * inv);
        pk.y = cvt_pk_bf16(o[n][2] * inv, o[n][3] * inv);
        *(uint2*)&y[((size_t)(bb * T_ + qrow)) * C_ + h * 64 + n * 16 + quad * 4] = pk;
    }
}

// ---------------------------------------------------------------------------
// Output projection: y[4096][1024] @ WprojT[1024][1024]^T + bias -> fp32 out.
// 128x64 tile (512 blocks, 48 KB LDS -> 3 blocks/CU).
// ---------------------------------------------------------------------------
__global__ __launch_bounds__(256, 3)
void proj_gemm(const u16* __restrict__ A, const u16* __restrict__ BT,
               const float* __restrict__ bias, float* __restrict__ out) {
    __shared__ __align__(16) u16 As[2 * 128 * 64];
    __shared__ __align__(16) u16 Bs[2 * 64 * 64];
    const int m0 = blockIdx.y * 128, n0 = blockIdx.x * 64;
    const int tid = threadIdx.x;
    const int lane = tid & 63, w = tid >> 6;
    const int l15 = lane & 15, quad = lane >> 4;
    const int row0 = (w & 1) * 64, col0 = (w >> 1) * 32;
    const int srow = lane >> 3;
    const int schunk = (lane & 7) ^ srow;
    f32x4 acc[4][2] = {};

    auto stage = [&](int buf, int k0) {
        #pragma unroll
        for (int j = 0; j < 4; ++j) {
            int rbase = w * 32 + j * 8;
            const u16* ga = A + (size_t)(m0 + rbase + srow) * 1024 + k0 + schunk * 8;
            __builtin_amdgcn_global_load_lds((const AS1 void*)ga,
                (AS3 void*)(As + buf * (128 * 64) + rbase * 64), 16, 0, 0);
        }
        #pragma unroll
        for (int j = 0; j < 2; ++j) {
            int rbase = w * 16 + j * 8;
            const u16* gb = BT + (size_t)(n0 + rbase + srow) * 1024 + k0 + schunk * 8;
            __builtin_amdgcn_global_load_lds((const AS1 void*)gb,
                (AS3 void*)(Bs + buf * (64 * 64) + rbase * 64), 16, 0, 0);
        }
    };

    stage(0, 0);
    #pragma unroll
    for (int it = 0; it < 16; ++it) {
        const int cur = it & 1;
        if (it + 1 < 16) {
            stage(cur ^ 1, (it + 1) * 64);
            asm volatile("s_waitcnt vmcnt(6)\n\ts_barrier" ::: "memory");
        } else {
            asm volatile("s_waitcnt vmcnt(0)\n\ts_barrier" ::: "memory");
        }
        const u16* Ac = As + cur * (128 * 64);
        const u16* Bc = Bs + cur * (64 * 64);
        #pragma unroll
        for (int s = 0; s < 2; ++s) {
            short8 a[4], b[2];
            #pragma unroll
            for (int rt = 0; rt < 4; ++rt) {
                int row = row0 + rt * 16 + l15;
                a[rt] = *(const short8*)&Ac[row * 64 + (((s * 4 + quad) ^ (l15 & 7)) * 8)];
            }
            #pragma unroll
            for (int ct = 0; ct < 2; ++ct) {
                int row = col0 + ct * 16 + l15;
                b[ct] = *(const short8*)&Bc[row * 64 + (((s * 4 + quad) ^ (l15 & 7)) * 8)];
            }
            #pragma unroll
            for (int rt = 0; rt < 4; ++rt)
                #pragma unroll
                for (int ct = 0; ct < 2; ++ct)
                    acc[rt][ct] = __builtin_amdgcn_mfma_f32_16x16x32_bf16(a[rt], b[ct], acc[rt][ct], 0, 0, 0);
        }
        asm volatile("s_waitcnt lgkmcnt(0)\n\ts_barrier" ::: "memory");
    }

    #pragma unroll
    for (int ct = 0; ct < 2; ++ct) {
        int n = n0 + col0 + ct * 16 + l15;
        float bv = bias[n];
        #pragma unroll
        for (int rt = 0; rt < 4; ++rt) {
            int mb = m0 + row0 + rt * 16 + quad * 4;
            f32x4 v4 = acc[rt][ct];
            #pragma unroll
            for (int r = 0; r < 4; ++r)
                out[(size_t)(mb + r) * 1024 + n] = v4[r] + bv;
        }
    }
}

// ---------------------------------------------------------------------------
extern "C" void kernel_launch(void* const* d_in, const int* in_sizes, int n_in,
                              void* d_out, int out_size, void* d_ws, size_t ws_size,
                              hipStream_t stream) {
    const float* x     = (const float*)d_in[0];
    const float* Wqkv  = (const float*)d_in[1];
    const float* bqkv  = (const float*)d_in[2];
    const float* Wproj = (const float*)d_in[3];
    const float* bproj = (const float*)d_in[4];

    u16* xb     = (u16*)d_ws;
    u16* WqkvT  = xb + (size_t)4 * 1024 * 1024;
    u16* WprojT = WqkvT + (size_t)3 * 1024 * 1024;
    u16* q      = WprojT + (size_t)1024 * 1024;
    u16* kk     = q + (size_t)4 * 1024 * 1024;
    u16* vT     = kk + (size_t)4 * 1024 * 1024;
    u16* y      = vT + (size_t)4 * 1024 * 1024;

    conv_all<<<5120, 256, 0, stream>>>(x, xb, Wqkv, WqkvT, Wproj, WprojT);
    qkv_gemm<<<dim3(N3C / 128, BT_ / 128), 256, 0, stream>>>(xb, WqkvT, bqkv, q, kk, vT);
    attn<<<1024, 256, 0, stream>>>(q, kk, vT, y);
    proj_gemm<<<dim3(C_ / 64, BT_ / 128), 256, 0, stream>>>(y, WprojT, bproj, (float*)d_out);
}